// Round 12
// baseline (2637.925 us; speedup 1.0000x reference)
//
#include <hip/hip_runtime.h>
#include <hip/hip_bf16.h>
#include <stdint.h>

#define NB 8
#define NPTS 8192
#define NCH 64
#define NPOINT 2048
#define NSAMPLE 32
#define R2 0.04f

#define DPP_MAX_STEP(C) { \
  int lo2_ = __builtin_amdgcn_update_dpp(0, (int)(unsigned int)key, (C), 0xf, 0xf, true); \
  int hi2_ = __builtin_amdgcn_update_dpp(0, (int)(unsigned int)(key>>32), (C), 0xf, 0xf, true); \
  unsigned long long k2_ = ((unsigned long long)(unsigned int)hi2_ << 32) | (unsigned int)lo2_; \
  if (k2_ > key) key = k2_; }

// ---------------------------------------------------------------------------
// FPS: one block (256 thr = 4 waves) per batch; 32 pts/lane in registers.
// Same exact arithmetic + u64-key DPP reduce as R9; smaller barrier (4 waves,
// 1/SIMD), 4-key tree (2 b128 loads, 3 maxes). Per-SIMD burst work unchanged.
// ---------------------------------------------------------------------------
__global__ __launch_bounds__(256) void fps_kernel(const float* __restrict__ xyz,
                                                  float* __restrict__ out)
{
  const int t = threadIdx.x;
  const int wv = t >> 6, lane = t & 63;
  const int b = blockIdx.x;
  const float* xb = xyz + (size_t)b*3*NPTS;
  __shared__ float s_px[NPTS], s_py[NPTS], s_pz[NPTS];   // 96 KB point mirror
  __shared__ float s_ox[NPOINT], s_oy[NPOINT], s_oz[NPOINT]; // 24 KB out stash
  __shared__ unsigned long long s_key[2][4];
  for (int e=t; e<NPTS; e+=256){
    s_px[e]=xb[e]; s_py[e]=xb[NPTS+e]; s_pz[e]=xb[2*NPTS+e];
  }
  // lane owns idx = wv*2048 + k*64 + lane, k ascending -> first-index ties
  float px[32], py[32], pz[32], dist[32];
  const int base = (wv<<11) + lane;
  #pragma unroll
  for (int k=0;k<32;k++){
    int i = base + (k<<6);
    px[k]=xb[i]; py[k]=xb[NPTS+i]; pz[k]=xb[2*NPTS+i];
    dist[k]=1e10f;
  }
  __syncthreads();
  float cx = s_px[0], cy = s_py[0], cz = s_pz[0];   // far_0 = 0
  for (int s=0;s<NPOINT;s++){
    if (t==0){ s_ox[s]=cx; s_oy[s]=cy; s_oz[s]=cz; }
    float best = -1.0f; int bidx = 0;
    #pragma unroll
    for (int k=0;k<32;k++){
      float dx=__fsub_rn(px[k],cx), dy=__fsub_rn(py[k],cy), dz=__fsub_rn(pz[k],cz);
      float d = __fadd_rn(__fadd_rn(__fmul_rn(dx,dx),__fmul_rn(dy,dy)),__fmul_rn(dz,dz));
      float nd = d < dist[k] ? d : dist[k];
      dist[k]=nd;
      if (nd > best){ best = nd; bidx = base + (k<<6); }   // strict > keeps first idx
    }
    unsigned long long key = ((unsigned long long)__float_as_uint(best) << 13)
                           | (unsigned long long)(8191 - bidx);
    DPP_MAX_STEP(0x111)
    DPP_MAX_STEP(0x112)
    DPP_MAX_STEP(0x114)
    DPP_MAX_STEP(0x118)
    DPP_MAX_STEP(0x142)
    DPP_MAX_STEP(0x143)
    if (lane==63) s_key[s&1][wv] = key;
    __syncthreads();
    const unsigned long long* kr = s_key[s&1];
    unsigned long long k0=kr[0],k1=kr[1],k2=kr[2],k3=kr[3];
    unsigned long long m01=k0>k1?k0:k1, m23=k2>k3?k2:k3;
    unsigned long long mk = m01>m23?m01:m23;
    const int far = 8191 - (int)(mk & 8191ull);
    cx = s_px[far]; cy = s_py[far]; cz = s_pz[far];
  }
  __syncthreads();
  float* oxb = out + (size_t)b*3*NPOINT;
  for (int e=t; e<NPOINT; e+=256){
    oxb[e]          = s_ox[e];
    oxb[NPOINT+e]   = s_oy[e];
    oxb[2*NPOINT+e] = s_oz[e];
  }
}

// ---------------------------------------------------------------------------
// Transpose points [b][c][n] -> pt [b][n][c]
// ---------------------------------------------------------------------------
__global__ __launch_bounds__(256) void transpose_kernel(const float* __restrict__ points,
                                                        float* __restrict__ pt)
{
  __shared__ float tile[64][65];
  const int t = threadIdx.x;
  const int b  = blockIdx.x >> 7;
  const int n0 = (blockIdx.x & 127) << 6;
  const int tx = t & 63, ty = t >> 6;
  #pragma unroll
  for (int r=0; r<16; r++){
    const int c = ty*16 + r;
    tile[c][tx] = points[(size_t)b*NCH*NPTS + (size_t)c*NPTS + n0 + tx];
  }
  __syncthreads();
  #pragma unroll
  for (int r=0; r<16; r++){
    const int n = ty*16 + r;
    pt[((size_t)b*NPTS + n0 + n)*64 + tx] = tile[tx][n];
  }
}

// ---------------------------------------------------------------------------
// Fused ball query + MLP layer 1, register-tiled GEMM (8 samples x 8 outs).
// ---------------------------------------------------------------------------
__global__ __launch_bounds__(128) void ballmlp1_kernel(
    const float* __restrict__ xyz, const float* __restrict__ pt,
    const float* __restrict__ nxyz,
    const float* __restrict__ W1, const float* __restrict__ b1,
    float* __restrict__ z, float* __restrict__ part)
{
  __shared__ float wl[67*64];        // W [c][o]
  __shared__ float fl[67*128];       // f [c][s]; reused for stats staging
  __shared__ int s_buf[4][NSAMPLE];
  __shared__ int s_cnt[4];
  __shared__ float s_ctr[4][3];
  const int t = threadIdx.x;
  const int blk = blockIdx.x;
  for (int e=t; e<67*64; e+=128){
    int o = e/67, c = e - o*67;
    wl[c*64+o] = W1[e];
  }
  const int wv = t>>6, lane = t&63;
  for (int sub=0; sub<2; sub++){
    const int gi2 = wv*2 + sub;
    const int g = blk*4 + gi2;
    const int b = g >> 11;
    const int s = g & 2047;
    const float* ob = nxyz + (size_t)b*3*NPOINT;
    const float cx = ob[s], cy = ob[NPOINT+s], cz = ob[2*NPOINT+s];
    if (lane==0){ s_ctr[gi2][0]=cx; s_ctr[gi2][1]=cy; s_ctr[gi2][2]=cz; }
    const float csum = __fadd_rn(__fadd_rn(__fmul_rn(cx,cx),__fmul_rn(cy,cy)),__fmul_rn(cz,cz));
    const float* xb = xyz + (size_t)b*3*NPTS;
    int cnt = 0;
    for (int c0=0; c0<NPTS; c0+=64){
      const int i = c0 + lane;
      float x=xb[i], y=xb[NPTS+i], zz=xb[2*NPTS+i];
      float dot  = __fmaf_rn(cz, zz, __fmaf_rn(cy, y, __fmul_rn(cx, x)));
      float dsum = __fadd_rn(__fadd_rn(__fmul_rn(x,x),__fmul_rn(y,y)),__fmul_rn(zz,zz));
      float sqr  = __fadd_rn(__fadd_rn(__fmul_rn(-2.0f,dot), csum), dsum);
      bool in = (sqr <= R2);
      unsigned long long mm = __ballot(in);
      int rank = cnt + __popcll(mm & ((1ull<<lane)-1ull));
      if (in && rank < NSAMPLE) s_buf[gi2][rank] = i;
      cnt += (int)__popcll(mm);
      if (cnt >= NSAMPLE) break;
    }
    if (lane==0) s_cnt[gi2] = cnt;
  }
  __syncthreads();
  {
    const int gi = t>>5, lane2 = t&31;
    const int g = blk*4 + gi;
    const int b = g >> 11;
    const int cnt = s_cnt[gi];
    const int first = s_buf[gi][0];
    const int idx = (lane2 < cnt) ? s_buf[gi][lane2] : first;
    const float* xb = xyz + (size_t)b*3*NPTS;
    fl[0*128+t] = __fsub_rn(xb[idx],        s_ctr[gi][0]);
    fl[1*128+t] = __fsub_rn(xb[NPTS+idx],   s_ctr[gi][1]);
    fl[2*128+t] = __fsub_rn(xb[2*NPTS+idx], s_ctr[gi][2]);
    const float* pr = pt + ((size_t)b*NPTS + idx)*64;
    #pragma unroll
    for (int q=0;q<16;q++){
      float4 v = *(const float4*)(pr + q*4);
      fl[(3+q*4+0)*128+t]=v.x; fl[(3+q*4+1)*128+t]=v.y;
      fl[(3+q*4+2)*128+t]=v.z; fl[(3+q*4+3)*128+t]=v.w;
    }
  }
  __syncthreads();
  const int tx = t & 15, ty = t >> 4;
  float acc[64];
  #pragma unroll
  for (int i=0;i<64;i++) acc[i]=0.0f;
  for (int c=0;c<67;c++){
    float4 fa = *(const float4*)&fl[c*128 + tx*8];
    float4 fb = *(const float4*)&fl[c*128 + tx*8 + 4];
    float4 wa = *(const float4*)&wl[c*64 + ty*8];
    float4 wb = *(const float4*)&wl[c*64 + ty*8 + 4];
    float fv[8] = {fa.x,fa.y,fa.z,fa.w,fb.x,fb.y,fb.z,fb.w};
    float wv8[8] = {wa.x,wa.y,wa.z,wa.w,wb.x,wb.y,wb.z,wb.w};
    #pragma unroll
    for (int oo=0;oo<8;oo++)
      #pragma unroll
      for (int ss=0;ss<8;ss++)
        acc[oo*8+ss] = __fmaf_rn(fv[ss], wv8[oo], acc[oo*8+ss]);
  }
  #pragma unroll
  for (int oo=0;oo<8;oo++){
    const float bb = b1[ty*8+oo];
    #pragma unroll
    for (int ss=0;ss<8;ss++) acc[oo*8+ss] = __fadd_rn(acc[oo*8+ss], bb);
  }
  float* zb = z + (size_t)blk*8192;
  #pragma unroll
  for (int oo=0;oo<8;oo++){
    float4 v0; v0.x=acc[oo*8+0]; v0.y=acc[oo*8+1]; v0.z=acc[oo*8+2]; v0.w=acc[oo*8+3];
    float4 v1; v1.x=acc[oo*8+4]; v1.y=acc[oo*8+5]; v1.z=acc[oo*8+6]; v1.w=acc[oo*8+7];
    *(float4*)(zb + (ty*8+oo)*128 + tx*8)     = v0;
    *(float4*)(zb + (ty*8+oo)*128 + tx*8 + 4) = v1;
  }
  __syncthreads();
  float* spA = fl;                 // [64][17]
  float* spQ = fl + 64*17;
  #pragma unroll
  for (int oo=0;oo<8;oo++){
    float sA=0.f, sQ=0.f;
    #pragma unroll
    for (int ss=0;ss<8;ss++){
      float v = acc[oo*8+ss];
      sA += v; sQ = __fmaf_rn(v,v,sQ);
    }
    spA[(ty*8+oo)*17 + tx] = sA;
    spQ[(ty*8+oo)*17 + tx] = sQ;
  }
  __syncthreads();
  if (t < 64){
    float A=0.f, Q=0.f;
    #pragma unroll
    for (int j=0;j<16;j++){ A += spA[t*17+j]; Q += spQ[t*17+j]; }
    part[(size_t)blk*128 + t]      = A;
    part[(size_t)blk*128 + 64 + t] = Q;
  }
}

// ---------------------------------------------------------------------------
// MLP layer 2: register-tiled GEMM, in-place z tile update.
// ---------------------------------------------------------------------------
__global__ __launch_bounds__(128) void mlp2_kernel(
    float* __restrict__ z, const float* __restrict__ ab1,
    const float* __restrict__ W2, const float* __restrict__ b2,
    float* __restrict__ part)
{
  __shared__ float wl[64*64];
  __shared__ float fl[64*128];
  __shared__ float s_ab[128];
  const int t = threadIdx.x;
  for (int e=t; e<64*64; e+=128){
    int o = e>>6, c = e&63;
    wl[c*64+o] = W2[e];
  }
  if (t<128) s_ab[t] = ab1[t];
  __syncthreads();
  float* zb = z + (size_t)blockIdx.x*8192;
  for (int c=0;c<64;c++){
    float v = zb[c*128 + t];
    float a = __fmaf_rn(v, s_ab[c], s_ab[64+c]);
    fl[c*128 + t] = a > 0.f ? a : 0.f;
  }
  __syncthreads();
  const int tx = t & 15, ty = t >> 4;
  float acc[64];
  #pragma unroll
  for (int i=0;i<64;i++) acc[i]=0.0f;
  for (int c=0;c<64;c++){
    float4 fa = *(const float4*)&fl[c*128 + tx*8];
    float4 fb = *(const float4*)&fl[c*128 + tx*8 + 4];
    float4 wa = *(const float4*)&wl[c*64 + ty*8];
    float4 wb = *(const float4*)&wl[c*64 + ty*8 + 4];
    float fv[8] = {fa.x,fa.y,fa.z,fa.w,fb.x,fb.y,fb.z,fb.w};
    float wv8[8] = {wa.x,wa.y,wa.z,wa.w,wb.x,wb.y,wb.z,wb.w};
    #pragma unroll
    for (int oo=0;oo<8;oo++)
      #pragma unroll
      for (int ss=0;ss<8;ss++)
        acc[oo*8+ss] = __fmaf_rn(fv[ss], wv8[oo], acc[oo*8+ss]);
  }
  #pragma unroll
  for (int oo=0;oo<8;oo++){
    const float bb = b2[ty*8+oo];
    #pragma unroll
    for (int ss=0;ss<8;ss++) acc[oo*8+ss] = __fadd_rn(acc[oo*8+ss], bb);
  }
  #pragma unroll
  for (int oo=0;oo<8;oo++){
    float4 v0; v0.x=acc[oo*8+0]; v0.y=acc[oo*8+1]; v0.z=acc[oo*8+2]; v0.w=acc[oo*8+3];
    float4 v1; v1.x=acc[oo*8+4]; v1.y=acc[oo*8+5]; v1.z=acc[oo*8+6]; v1.w=acc[oo*8+7];
    *(float4*)(zb + (ty*8+oo)*128 + tx*8)     = v0;
    *(float4*)(zb + (ty*8+oo)*128 + tx*8 + 4) = v1;
  }
  __syncthreads();
  float* spA = fl;
  float* spQ = fl + 64*17;
  #pragma unroll
  for (int oo=0;oo<8;oo++){
    float sA=0.f, sQ=0.f;
    #pragma unroll
    for (int ss=0;ss<8;ss++){
      float v = acc[oo*8+ss];
      sA += v; sQ = __fmaf_rn(v,v,sQ);
    }
    spA[(ty*8+oo)*17 + tx] = sA;
    spQ[(ty*8+oo)*17 + tx] = sQ;
  }
  __syncthreads();
  if (t < 64){
    float A=0.f, Q=0.f;
    #pragma unroll
    for (int j=0;j<16;j++){ A += spA[t*17+j]; Q += spQ[t*17+j]; }
    part[(size_t)blockIdx.x*128 + t]      = A;
    part[(size_t)blockIdx.x*128 + 64 + t] = Q;
  }
}

// ---------------------------------------------------------------------------
// MLP layer 3 + group max: 256 thr, tile 128 samples x 128 outs (8x8/thread).
// ---------------------------------------------------------------------------
__global__ __launch_bounds__(256) void mlp3_kernel(
    const float* __restrict__ z, const float* __restrict__ ab2,
    const float* __restrict__ W3, const float* __restrict__ b3,
    float* __restrict__ gmax, float* __restrict__ part)
{
  __shared__ float wl[64*128];       // W [c][o]; reused: spA/spQ [128][17]
  __shared__ float fl[64*128];       // f [c][s]; reused: sm [16][132]
  __shared__ float s_ab[128];
  const int t = threadIdx.x;
  const int blk = blockIdx.x;
  for (int e=t; e<64*128; e+=256){
    int o = e>>6, c = e&63;
    wl[c*128+o] = W3[e];
  }
  if (t<128) s_ab[t] = ab2[t];
  __syncthreads();
  const float* zb = z + (size_t)blk*8192;
  for (int e=t; e<64*128; e+=256){
    int c = e>>7, s = e&127;
    float v = zb[c*128 + s];
    float a = __fmaf_rn(v, s_ab[c], s_ab[64+c]);
    fl[c*128 + s] = a > 0.f ? a : 0.f;
  }
  __syncthreads();
  const int tx = t & 15, ty = t >> 4;
  float acc[64];
  #pragma unroll
  for (int i=0;i<64;i++) acc[i]=0.0f;
  for (int c=0;c<64;c++){
    float4 fa = *(const float4*)&fl[c*128 + tx*8];
    float4 fb = *(const float4*)&fl[c*128 + tx*8 + 4];
    float4 wa = *(const float4*)&wl[c*128 + ty*8];
    float4 wb = *(const float4*)&wl[c*128 + ty*8 + 4];
    float fv[8] = {fa.x,fa.y,fa.z,fa.w,fb.x,fb.y,fb.z,fb.w};
    float wv8[8] = {wa.x,wa.y,wa.z,wa.w,wb.x,wb.y,wb.z,wb.w};
    #pragma unroll
    for (int oo=0;oo<8;oo++)
      #pragma unroll
      for (int ss=0;ss<8;ss++)
        acc[oo*8+ss] = __fmaf_rn(fv[ss], wv8[oo], acc[oo*8+ss]);
  }
  #pragma unroll
  for (int oo=0;oo<8;oo++){
    const float bb = b3[ty*8+oo];
    #pragma unroll
    for (int ss=0;ss<8;ss++) acc[oo*8+ss] = __fadd_rn(acc[oo*8+ss], bb);
  }
  __syncthreads();
  float* spA = wl;                    // [128][17]
  float* spQ = wl + 128*17;
  float* sm  = fl;                    // [16][132]
  #pragma unroll
  for (int oo=0;oo<8;oo++){
    float sA=0.f, sQ=0.f, mx=acc[oo*8+0];
    #pragma unroll
    for (int ss=0;ss<8;ss++){
      float v = acc[oo*8+ss];
      sA += v; sQ = __fmaf_rn(v,v,sQ);
      mx = v > mx ? v : mx;
    }
    spA[(ty*8+oo)*17 + tx] = sA;
    spQ[(ty*8+oo)*17 + tx] = sQ;
    sm[tx*132 + ty*8+oo] = mx;
  }
  __syncthreads();
  if (t < 128){
    float A=0.f, Q=0.f;
    #pragma unroll
    for (int j=0;j<16;j++){ A += spA[t*17+j]; Q += spQ[t*17+j]; }
    part[(size_t)blk*256 + t]       = A;
    part[(size_t)blk*256 + 128 + t] = Q;
  }
  #pragma unroll
  for (int r=0;r<2;r++){
    const int id = t + r*256;
    const int g = id >> 7, o = id & 127;
    float m0 = sm[(g*4+0)*132 + o];
    float m1 = sm[(g*4+1)*132 + o];
    float m2 = sm[(g*4+2)*132 + o];
    float m3 = sm[(g*4+3)*132 + o];
    float mm = m0 > m1 ? m0 : m1;
    float nn = m2 > m3 ? m2 : m3;
    mm = mm > nn ? mm : nn;
    gmax[((size_t)blk*4 + g)*128 + o] = mm;
  }
}

// ---------------------------------------------------------------------------
// BN stats finalize
// ---------------------------------------------------------------------------
__global__ __launch_bounds__(64) void reduce_kernel(const float* __restrict__ part,
    const float* __restrict__ gw, const float* __restrict__ bew,
    float* __restrict__ ab, int cout, int nblk)
{
  const int o = blockIdx.x, t = threadIdx.x;
  const int stride = 2*cout;
  float A=0.f, Q=0.f;
  for (int i=t;i<nblk;i+=64){
    A += part[(size_t)i*stride + o];
    Q += part[(size_t)i*stride + cout + o];
  }
  #pragma unroll
  for (int off=1; off<64; off<<=1){
    A += __shfl_xor(A, off, 64);
    Q += __shfl_xor(Q, off, 64);
  }
  if (t==0){
    const float inv = 1.0f/524288.0f;
    float mean = A*inv;
    float var  = Q*inv - mean*mean;
    float a = gw[o] / sqrtf(var + 1e-5f);
    ab[o] = a;
    ab[cout+o] = bew[o] - mean*a;
  }
}

// ---------------------------------------------------------------------------
// Final: out_points[b][o][s] = relu(gmax*a3 + shift3), transposed tile
// ---------------------------------------------------------------------------
__global__ __launch_bounds__(256) void final_kernel(const float* __restrict__ gmax,
    const float* __restrict__ ab3, float* __restrict__ out)
{
  __shared__ float tile[32*129];
  __shared__ float s_a[128], s_b[128];
  const int t = threadIdx.x;
  const int b = blockIdx.x >> 6;
  const int s0 = (blockIdx.x & 63)*32;
  if (t<128){ s_a[t]=ab3[t]; s_b[t]=ab3[128+t]; }
  const float* gp = gmax + ((size_t)b*NPOINT + s0)*128;
  for (int e=t; e<32*32; e+=256){
    int r = e>>5, q = e&31;
    float4 v = *(const float4*)(gp + r*128 + q*4);
    tile[r*129 + q*4+0]=v.x; tile[r*129 + q*4+1]=v.y;
    tile[r*129 + q*4+2]=v.z; tile[r*129 + q*4+3]=v.w;
  }
  __syncthreads();
  float* ob = out + 49152 + (size_t)b*128*NPOINT;
  for (int e=t; e<128*32; e+=256){
    int o = e>>5, ls = e&31;
    float v = tile[ls*129 + o];
    v = __fmaf_rn(v, s_a[o], s_b[o]);
    v = v > 0.f ? v : 0.f;
    ob[(size_t)o*NPOINT + s0 + ls] = v;
  }
}

extern "C" void kernel_launch(void* const* d_in, const int* in_sizes, int n_in,
                              void* d_out, int out_size, void* d_ws, size_t ws_size,
                              hipStream_t stream)
{
  const float* xyz    = (const float*)d_in[0];
  const float* points = (const float*)d_in[1];
  const float* W1 = (const float*)d_in[2];
  const float* b1 = (const float*)d_in[3];
  const float* g1 = (const float*)d_in[4];
  const float* be1= (const float*)d_in[5];
  const float* W2 = (const float*)d_in[6];
  const float* b2 = (const float*)d_in[7];
  const float* g2 = (const float*)d_in[8];
  const float* be2= (const float*)d_in[9];
  const float* W3 = (const float*)d_in[10];
  const float* b3 = (const float*)d_in[11];
  const float* g3 = (const float*)d_in[12];
  const float* be3= (const float*)d_in[13];
  float* out = (float*)d_out;
  char* ws = (char*)d_ws;
  float* z     = (float*)(ws);                            // 134,217,728
  float* pt    = (float*)(ws + 134217728);                //  16,777,216 (alias)
  float* gmax  = (float*)(ws + 134217728);                //   8,388,608
  float* part3 = (float*)(ws + 142606336);                //   4,194,304
  float* part2 = (float*)(ws + 146800640);                //   2,097,152
  float* part1 = (float*)(ws + 150994944);                //   2,097,152
  float* ab1   = (float*)(ws + 153092096);                //   512
  float* ab2   = (float*)(ws + 153092608);                //   512
  float* ab3   = (float*)(ws + 153093120);                //   1024

  hipLaunchKernelGGL(fps_kernel,      dim3(NB),   dim3(256), 0, stream, xyz, out);
  hipLaunchKernelGGL(transpose_kernel,dim3(1024), dim3(256), 0, stream, points, pt);
  hipLaunchKernelGGL(ballmlp1_kernel, dim3(4096), dim3(128), 0, stream, xyz, pt, out, W1, b1, z, part1);
  hipLaunchKernelGGL(reduce_kernel,   dim3(64),   dim3(64),  0, stream, part1, g1, be1, ab1, 64, 4096);
  hipLaunchKernelGGL(mlp2_kernel,     dim3(4096), dim3(128), 0, stream, z, ab1, W2, b2, part2);
  hipLaunchKernelGGL(reduce_kernel,   dim3(64),   dim3(64),  0, stream, part2, g2, be2, ab2, 64, 4096);
  hipLaunchKernelGGL(mlp3_kernel,     dim3(4096), dim3(256), 0, stream, z, ab2, W3, b3, gmax, part3);
  hipLaunchKernelGGL(reduce_kernel,   dim3(128),  dim3(64),  0, stream, part3, g3, be3, ab3, 128, 4096);
  hipLaunchKernelGGL(final_kernel,    dim3(512),  dim3(256), 0, stream, gmax, ab3, out);
}

// Round 13
// 2459.554 us; speedup vs baseline: 1.0725x; 1.0725x over previous
//
#include <hip/hip_runtime.h>
#include <hip/hip_bf16.h>
#include <stdint.h>

#define NB 8
#define NPTS 8192
#define NCH 64
#define NPOINT 2048
#define NSAMPLE 32
#define R2 0.04f

typedef __attribute__((ext_vector_type(2))) float f32x2;

#define DPP_MAX_STEP(C) { \
  int lo2_ = __builtin_amdgcn_update_dpp(0, (int)(unsigned int)key, (C), 0xf, 0xf, true); \
  int hi2_ = __builtin_amdgcn_update_dpp(0, (int)(unsigned int)(key>>32), (C), 0xf, 0xf, true); \
  unsigned long long k2_ = ((unsigned long long)(unsigned int)hi2_ << 32) | (unsigned int)lo2_; \
  if (k2_ > key) key = k2_; }

// ---------------------------------------------------------------------------
// FPS: R9 structure (8 waves, LDS point mirror, u64-key DPP reduce, 1 barrier)
// with the distance burst in packed f32 (v_pk_add/v_pk_mul inline asm).
// Exact IEEE semantics preserved: pk add/mul are per-half identical to scalar
// __fadd_rn/__fmul_rn; dx = px + (-cx) == __fsub_rn(px,cx); no fma anywhere.
// Pair order (2k,2k+1) with nd0 before nd1 keeps first-index tie-break.
// ---------------------------------------------------------------------------
__global__ __launch_bounds__(512) void fps_kernel(const float* __restrict__ xyz,
                                                  float* __restrict__ out)
{
  const int t = threadIdx.x;
  const int wv = t >> 6, lane = t & 63;
  const int b = blockIdx.x;
  const float* xb = xyz + (size_t)b*3*NPTS;
  __shared__ float s_px[NPTS], s_py[NPTS], s_pz[NPTS];   // 96 KB point mirror
  __shared__ float s_ox[NPOINT], s_oy[NPOINT], s_oz[NPOINT]; // 24 KB out stash
  __shared__ unsigned long long s_key[2][8];
  for (int e=t; e<NPTS; e+=512){
    s_px[e]=xb[e]; s_py[e]=xb[NPTS+e]; s_pz[e]=xb[2*NPTS+e];
  }
  // lane owns idx = wv*1024 + k*64 + lane, k = 2j+h ascending
  f32x2 px[8], py[8], pz[8], dist[8];
  const int base = (wv<<10) + lane;
  #pragma unroll
  for (int j=0;j<8;j++){
    int i0 = base + (2*j)*64, i1 = i0 + 64;
    px[j] = (f32x2){xb[i0],        xb[i1]};
    py[j] = (f32x2){xb[NPTS+i0],   xb[NPTS+i1]};
    pz[j] = (f32x2){xb[2*NPTS+i0], xb[2*NPTS+i1]};
    dist[j] = (f32x2){1e10f, 1e10f};
  }
  __syncthreads();
  float cx = s_px[0], cy = s_py[0], cz = s_pz[0];   // far_0 = 0
  for (int s=0;s<NPOINT;s++){
    if (t==0){ s_ox[s]=cx; s_oy[s]=cy; s_oz[s]=cz; }
    const f32x2 ncx = (f32x2){-cx,-cx};
    const f32x2 ncy = (f32x2){-cy,-cy};
    const f32x2 ncz = (f32x2){-cz,-cz};
    float best = -1.0f; int bidx = 0;
    #pragma unroll
    for (int j=0;j<8;j++){
      f32x2 dx, dy, dz, xx, yy, zz, s1, d2;
      asm("v_pk_add_f32 %0, %1, %2" : "=v"(dx) : "v"(px[j]), "v"(ncx));
      asm("v_pk_add_f32 %0, %1, %2" : "=v"(dy) : "v"(py[j]), "v"(ncy));
      asm("v_pk_add_f32 %0, %1, %2" : "=v"(dz) : "v"(pz[j]), "v"(ncz));
      asm("v_pk_mul_f32 %0, %1, %1" : "=v"(xx) : "v"(dx));
      asm("v_pk_mul_f32 %0, %1, %1" : "=v"(yy) : "v"(dy));
      asm("v_pk_mul_f32 %0, %1, %1" : "=v"(zz) : "v"(dz));
      asm("v_pk_add_f32 %0, %1, %2" : "=v"(s1) : "v"(xx), "v"(yy));
      asm("v_pk_add_f32 %0, %1, %2" : "=v"(d2) : "v"(s1), "v"(zz));
      float nd0 = d2.x < dist[j].x ? d2.x : dist[j].x;
      float nd1 = d2.y < dist[j].y ? d2.y : dist[j].y;
      dist[j].x = nd0; dist[j].y = nd1;
      if (nd0 > best){ best = nd0; bidx = base + (2*j)*64; }     // strict >
      if (nd1 > best){ best = nd1; bidx = base + (2*j+1)*64; }
    }
    unsigned long long key = ((unsigned long long)__float_as_uint(best) << 13)
                           | (unsigned long long)(8191 - bidx);
    DPP_MAX_STEP(0x111)
    DPP_MAX_STEP(0x112)
    DPP_MAX_STEP(0x114)
    DPP_MAX_STEP(0x118)
    DPP_MAX_STEP(0x142)
    DPP_MAX_STEP(0x143)
    if (lane==63) s_key[s&1][wv] = key;
    __syncthreads();
    const unsigned long long* kr = s_key[s&1];
    unsigned long long k0=kr[0],k1=kr[1],k2=kr[2],k3=kr[3],
                       k4=kr[4],k5=kr[5],k6=kr[6],k7=kr[7];
    unsigned long long m01=k0>k1?k0:k1, m23=k2>k3?k2:k3;
    unsigned long long m45=k4>k5?k4:k5, m67=k6>k7?k6:k7;
    unsigned long long m03=m01>m23?m01:m23, m47=m45>m67?m45:m67;
    unsigned long long mk = m03>m47?m03:m47;
    const int far = 8191 - (int)(mk & 8191ull);
    cx = s_px[far]; cy = s_py[far]; cz = s_pz[far];
  }
  __syncthreads();
  float* oxb = out + (size_t)b*3*NPOINT;
  for (int e=t; e<NPOINT; e+=512){
    oxb[e]          = s_ox[e];
    oxb[NPOINT+e]   = s_oy[e];
    oxb[2*NPOINT+e] = s_oz[e];
  }
}

// ---------------------------------------------------------------------------
// Transpose points [b][c][n] -> pt [b][n][c]
// ---------------------------------------------------------------------------
__global__ __launch_bounds__(256) void transpose_kernel(const float* __restrict__ points,
                                                        float* __restrict__ pt)
{
  __shared__ float tile[64][65];
  const int t = threadIdx.x;
  const int b  = blockIdx.x >> 7;
  const int n0 = (blockIdx.x & 127) << 6;
  const int tx = t & 63, ty = t >> 6;
  #pragma unroll
  for (int r=0; r<16; r++){
    const int c = ty*16 + r;
    tile[c][tx] = points[(size_t)b*NCH*NPTS + (size_t)c*NPTS + n0 + tx];
  }
  __syncthreads();
  #pragma unroll
  for (int r=0; r<16; r++){
    const int n = ty*16 + r;
    pt[((size_t)b*NPTS + n0 + n)*64 + tx] = tile[tx][n];
  }
}

// ---------------------------------------------------------------------------
// Fused ball query + MLP layer 1, register-tiled GEMM (8 samples x 8 outs).
// ---------------------------------------------------------------------------
__global__ __launch_bounds__(128) void ballmlp1_kernel(
    const float* __restrict__ xyz, const float* __restrict__ pt,
    const float* __restrict__ nxyz,
    const float* __restrict__ W1, const float* __restrict__ b1,
    float* __restrict__ z, float* __restrict__ part)
{
  __shared__ float wl[67*64];        // W [c][o]
  __shared__ float fl[67*128];       // f [c][s]; reused for stats staging
  __shared__ int s_buf[4][NSAMPLE];
  __shared__ int s_cnt[4];
  __shared__ float s_ctr[4][3];
  const int t = threadIdx.x;
  const int blk = blockIdx.x;
  for (int e=t; e<67*64; e+=128){
    int o = e/67, c = e - o*67;
    wl[c*64+o] = W1[e];
  }
  const int wv = t>>6, lane = t&63;
  for (int sub=0; sub<2; sub++){
    const int gi2 = wv*2 + sub;
    const int g = blk*4 + gi2;
    const int b = g >> 11;
    const int s = g & 2047;
    const float* ob = nxyz + (size_t)b*3*NPOINT;
    const float cx = ob[s], cy = ob[NPOINT+s], cz = ob[2*NPOINT+s];
    if (lane==0){ s_ctr[gi2][0]=cx; s_ctr[gi2][1]=cy; s_ctr[gi2][2]=cz; }
    const float csum = __fadd_rn(__fadd_rn(__fmul_rn(cx,cx),__fmul_rn(cy,cy)),__fmul_rn(cz,cz));
    const float* xb = xyz + (size_t)b*3*NPTS;
    int cnt = 0;
    for (int c0=0; c0<NPTS; c0+=64){
      const int i = c0 + lane;
      float x=xb[i], y=xb[NPTS+i], zz=xb[2*NPTS+i];
      float dot  = __fmaf_rn(cz, zz, __fmaf_rn(cy, y, __fmul_rn(cx, x)));
      float dsum = __fadd_rn(__fadd_rn(__fmul_rn(x,x),__fmul_rn(y,y)),__fmul_rn(zz,zz));
      float sqr  = __fadd_rn(__fadd_rn(__fmul_rn(-2.0f,dot), csum), dsum);
      bool in = (sqr <= R2);
      unsigned long long mm = __ballot(in);
      int rank = cnt + __popcll(mm & ((1ull<<lane)-1ull));
      if (in && rank < NSAMPLE) s_buf[gi2][rank] = i;
      cnt += (int)__popcll(mm);
      if (cnt >= NSAMPLE) break;
    }
    if (lane==0) s_cnt[gi2] = cnt;
  }
  __syncthreads();
  {
    const int gi = t>>5, lane2 = t&31;
    const int g = blk*4 + gi;
    const int b = g >> 11;
    const int cnt = s_cnt[gi];
    const int first = s_buf[gi][0];
    const int idx = (lane2 < cnt) ? s_buf[gi][lane2] : first;
    const float* xb = xyz + (size_t)b*3*NPTS;
    fl[0*128+t] = __fsub_rn(xb[idx],        s_ctr[gi][0]);
    fl[1*128+t] = __fsub_rn(xb[NPTS+idx],   s_ctr[gi][1]);
    fl[2*128+t] = __fsub_rn(xb[2*NPTS+idx], s_ctr[gi][2]);
    const float* pr = pt + ((size_t)b*NPTS + idx)*64;
    #pragma unroll
    for (int q=0;q<16;q++){
      float4 v = *(const float4*)(pr + q*4);
      fl[(3+q*4+0)*128+t]=v.x; fl[(3+q*4+1)*128+t]=v.y;
      fl[(3+q*4+2)*128+t]=v.z; fl[(3+q*4+3)*128+t]=v.w;
    }
  }
  __syncthreads();
  const int tx = t & 15, ty = t >> 4;
  float acc[64];
  #pragma unroll
  for (int i=0;i<64;i++) acc[i]=0.0f;
  for (int c=0;c<67;c++){
    float4 fa = *(const float4*)&fl[c*128 + tx*8];
    float4 fb = *(const float4*)&fl[c*128 + tx*8 + 4];
    float4 wa = *(const float4*)&wl[c*64 + ty*8];
    float4 wb = *(const float4*)&wl[c*64 + ty*8 + 4];
    float fv[8] = {fa.x,fa.y,fa.z,fa.w,fb.x,fb.y,fb.z,fb.w};
    float wv8[8] = {wa.x,wa.y,wa.z,wa.w,wb.x,wb.y,wb.z,wb.w};
    #pragma unroll
    for (int oo=0;oo<8;oo++)
      #pragma unroll
      for (int ss=0;ss<8;ss++)
        acc[oo*8+ss] = __fmaf_rn(fv[ss], wv8[oo], acc[oo*8+ss]);
  }
  #pragma unroll
  for (int oo=0;oo<8;oo++){
    const float bb = b1[ty*8+oo];
    #pragma unroll
    for (int ss=0;ss<8;ss++) acc[oo*8+ss] = __fadd_rn(acc[oo*8+ss], bb);
  }
  float* zb = z + (size_t)blk*8192;
  #pragma unroll
  for (int oo=0;oo<8;oo++){
    float4 v0; v0.x=acc[oo*8+0]; v0.y=acc[oo*8+1]; v0.z=acc[oo*8+2]; v0.w=acc[oo*8+3];
    float4 v1; v1.x=acc[oo*8+4]; v1.y=acc[oo*8+5]; v1.z=acc[oo*8+6]; v1.w=acc[oo*8+7];
    *(float4*)(zb + (ty*8+oo)*128 + tx*8)     = v0;
    *(float4*)(zb + (ty*8+oo)*128 + tx*8 + 4) = v1;
  }
  __syncthreads();
  float* spA = fl;                 // [64][17]
  float* spQ = fl + 64*17;
  #pragma unroll
  for (int oo=0;oo<8;oo++){
    float sA=0.f, sQ=0.f;
    #pragma unroll
    for (int ss=0;ss<8;ss++){
      float v = acc[oo*8+ss];
      sA += v; sQ = __fmaf_rn(v,v,sQ);
    }
    spA[(ty*8+oo)*17 + tx] = sA;
    spQ[(ty*8+oo)*17 + tx] = sQ;
  }
  __syncthreads();
  if (t < 64){
    float A=0.f, Q=0.f;
    #pragma unroll
    for (int j=0;j<16;j++){ A += spA[t*17+j]; Q += spQ[t*17+j]; }
    part[(size_t)blk*128 + t]      = A;
    part[(size_t)blk*128 + 64 + t] = Q;
  }
}

// ---------------------------------------------------------------------------
// MLP layer 2: register-tiled GEMM, in-place z tile update.
// ---------------------------------------------------------------------------
__global__ __launch_bounds__(128) void mlp2_kernel(
    float* __restrict__ z, const float* __restrict__ ab1,
    const float* __restrict__ W2, const float* __restrict__ b2,
    float* __restrict__ part)
{
  __shared__ float wl[64*64];
  __shared__ float fl[64*128];
  __shared__ float s_ab[128];
  const int t = threadIdx.x;
  for (int e=t; e<64*64; e+=128){
    int o = e>>6, c = e&63;
    wl[c*64+o] = W2[e];
  }
  if (t<128) s_ab[t] = ab1[t];
  __syncthreads();
  float* zb = z + (size_t)blockIdx.x*8192;
  for (int c=0;c<64;c++){
    float v = zb[c*128 + t];
    float a = __fmaf_rn(v, s_ab[c], s_ab[64+c]);
    fl[c*128 + t] = a > 0.f ? a : 0.f;
  }
  __syncthreads();
  const int tx = t & 15, ty = t >> 4;
  float acc[64];
  #pragma unroll
  for (int i=0;i<64;i++) acc[i]=0.0f;
  for (int c=0;c<64;c++){
    float4 fa = *(const float4*)&fl[c*128 + tx*8];
    float4 fb = *(const float4*)&fl[c*128 + tx*8 + 4];
    float4 wa = *(const float4*)&wl[c*64 + ty*8];
    float4 wb = *(const float4*)&wl[c*64 + ty*8 + 4];
    float fv[8] = {fa.x,fa.y,fa.z,fa.w,fb.x,fb.y,fb.z,fb.w};
    float wv8[8] = {wa.x,wa.y,wa.z,wa.w,wb.x,wb.y,wb.z,wb.w};
    #pragma unroll
    for (int oo=0;oo<8;oo++)
      #pragma unroll
      for (int ss=0;ss<8;ss++)
        acc[oo*8+ss] = __fmaf_rn(fv[ss], wv8[oo], acc[oo*8+ss]);
  }
  #pragma unroll
  for (int oo=0;oo<8;oo++){
    const float bb = b2[ty*8+oo];
    #pragma unroll
    for (int ss=0;ss<8;ss++) acc[oo*8+ss] = __fadd_rn(acc[oo*8+ss], bb);
  }
  #pragma unroll
  for (int oo=0;oo<8;oo++){
    float4 v0; v0.x=acc[oo*8+0]; v0.y=acc[oo*8+1]; v0.z=acc[oo*8+2]; v0.w=acc[oo*8+3];
    float4 v1; v1.x=acc[oo*8+4]; v1.y=acc[oo*8+5]; v1.z=acc[oo*8+6]; v1.w=acc[oo*8+7];
    *(float4*)(zb + (ty*8+oo)*128 + tx*8)     = v0;
    *(float4*)(zb + (ty*8+oo)*128 + tx*8 + 4) = v1;
  }
  __syncthreads();
  float* spA = fl;
  float* spQ = fl + 64*17;
  #pragma unroll
  for (int oo=0;oo<8;oo++){
    float sA=0.f, sQ=0.f;
    #pragma unroll
    for (int ss=0;ss<8;ss++){
      float v = acc[oo*8+ss];
      sA += v; sQ = __fmaf_rn(v,v,sQ);
    }
    spA[(ty*8+oo)*17 + tx] = sA;
    spQ[(ty*8+oo)*17 + tx] = sQ;
  }
  __syncthreads();
  if (t < 64){
    float A=0.f, Q=0.f;
    #pragma unroll
    for (int j=0;j<16;j++){ A += spA[t*17+j]; Q += spQ[t*17+j]; }
    part[(size_t)blockIdx.x*128 + t]      = A;
    part[(size_t)blockIdx.x*128 + 64 + t] = Q;
  }
}

// ---------------------------------------------------------------------------
// MLP layer 3 + group max: 256 thr, tile 128 samples x 128 outs (8x8/thread).
// ---------------------------------------------------------------------------
__global__ __launch_bounds__(256) void mlp3_kernel(
    const float* __restrict__ z, const float* __restrict__ ab2,
    const float* __restrict__ W3, const float* __restrict__ b3,
    float* __restrict__ gmax, float* __restrict__ part)
{
  __shared__ float wl[64*128];       // W [c][o]; reused: spA/spQ [128][17]
  __shared__ float fl[64*128];       // f [c][s]; reused: sm [16][132]
  __shared__ float s_ab[128];
  const int t = threadIdx.x;
  const int blk = blockIdx.x;
  for (int e=t; e<64*128; e+=256){
    int o = e>>6, c = e&63;
    wl[c*128+o] = W3[e];
  }
  if (t<128) s_ab[t] = ab2[t];
  __syncthreads();
  const float* zb = z + (size_t)blk*8192;
  for (int e=t; e<64*128; e+=256){
    int c = e>>7, s = e&127;
    float v = zb[c*128 + s];
    float a = __fmaf_rn(v, s_ab[c], s_ab[64+c]);
    fl[c*128 + s] = a > 0.f ? a : 0.f;
  }
  __syncthreads();
  const int tx = t & 15, ty = t >> 4;
  float acc[64];
  #pragma unroll
  for (int i=0;i<64;i++) acc[i]=0.0f;
  for (int c=0;c<64;c++){
    float4 fa = *(const float4*)&fl[c*128 + tx*8];
    float4 fb = *(const float4*)&fl[c*128 + tx*8 + 4];
    float4 wa = *(const float4*)&wl[c*128 + ty*8];
    float4 wb = *(const float4*)&wl[c*128 + ty*8 + 4];
    float fv[8] = {fa.x,fa.y,fa.z,fa.w,fb.x,fb.y,fb.z,fb.w};
    float wv8[8] = {wa.x,wa.y,wa.z,wa.w,wb.x,wb.y,wb.z,wb.w};
    #pragma unroll
    for (int oo=0;oo<8;oo++)
      #pragma unroll
      for (int ss=0;ss<8;ss++)
        acc[oo*8+ss] = __fmaf_rn(fv[ss], wv8[oo], acc[oo*8+ss]);
  }
  #pragma unroll
  for (int oo=0;oo<8;oo++){
    const float bb = b3[ty*8+oo];
    #pragma unroll
    for (int ss=0;ss<8;ss++) acc[oo*8+ss] = __fadd_rn(acc[oo*8+ss], bb);
  }
  __syncthreads();
  float* spA = wl;                    // [128][17]
  float* spQ = wl + 128*17;
  float* sm  = fl;                    // [16][132]
  #pragma unroll
  for (int oo=0;oo<8;oo++){
    float sA=0.f, sQ=0.f, mx=acc[oo*8+0];
    #pragma unroll
    for (int ss=0;ss<8;ss++){
      float v = acc[oo*8+ss];
      sA += v; sQ = __fmaf_rn(v,v,sQ);
      mx = v > mx ? v : mx;
    }
    spA[(ty*8+oo)*17 + tx] = sA;
    spQ[(ty*8+oo)*17 + tx] = sQ;
    sm[tx*132 + ty*8+oo] = mx;
  }
  __syncthreads();
  if (t < 128){
    float A=0.f, Q=0.f;
    #pragma unroll
    for (int j=0;j<16;j++){ A += spA[t*17+j]; Q += spQ[t*17+j]; }
    part[(size_t)blk*256 + t]       = A;
    part[(size_t)blk*256 + 128 + t] = Q;
  }
  #pragma unroll
  for (int r=0;r<2;r++){
    const int id = t + r*256;
    const int g = id >> 7, o = id & 127;
    float m0 = sm[(g*4+0)*132 + o];
    float m1 = sm[(g*4+1)*132 + o];
    float m2 = sm[(g*4+2)*132 + o];
    float m3 = sm[(g*4+3)*132 + o];
    float mm = m0 > m1 ? m0 : m1;
    float nn = m2 > m3 ? m2 : m3;
    mm = mm > nn ? mm : nn;
    gmax[((size_t)blk*4 + g)*128 + o] = mm;
  }
}

// ---------------------------------------------------------------------------
// BN stats finalize
// ---------------------------------------------------------------------------
__global__ __launch_bounds__(64) void reduce_kernel(const float* __restrict__ part,
    const float* __restrict__ gw, const float* __restrict__ bew,
    float* __restrict__ ab, int cout, int nblk)
{
  const int o = blockIdx.x, t = threadIdx.x;
  const int stride = 2*cout;
  float A=0.f, Q=0.f;
  for (int i=t;i<nblk;i+=64){
    A += part[(size_t)i*stride + o];
    Q += part[(size_t)i*stride + cout + o];
  }
  #pragma unroll
  for (int off=1; off<64; off<<=1){
    A += __shfl_xor(A, off, 64);
    Q += __shfl_xor(Q, off, 64);
  }
  if (t==0){
    const float inv = 1.0f/524288.0f;
    float mean = A*inv;
    float var  = Q*inv - mean*mean;
    float a = gw[o] / sqrtf(var + 1e-5f);
    ab[o] = a;
    ab[cout+o] = bew[o] - mean*a;
  }
}

// ---------------------------------------------------------------------------
// Final: out_points[b][o][s] = relu(gmax*a3 + shift3), transposed tile
// ---------------------------------------------------------------------------
__global__ __launch_bounds__(256) void final_kernel(const float* __restrict__ gmax,
    const float* __restrict__ ab3, float* __restrict__ out)
{
  __shared__ float tile[32*129];
  __shared__ float s_a[128], s_b[128];
  const int t = threadIdx.x;
  const int b = blockIdx.x >> 6;
  const int s0 = (blockIdx.x & 63)*32;
  if (t<128){ s_a[t]=ab3[t]; s_b[t]=ab3[128+t]; }
  const float* gp = gmax + ((size_t)b*NPOINT + s0)*128;
  for (int e=t; e<32*32; e+=256){
    int r = e>>5, q = e&31;
    float4 v = *(const float4*)(gp + r*128 + q*4);
    tile[r*129 + q*4+0]=v.x; tile[r*129 + q*4+1]=v.y;
    tile[r*129 + q*4+2]=v.z; tile[r*129 + q*4+3]=v.w;
  }
  __syncthreads();
  float* ob = out + 49152 + (size_t)b*128*NPOINT;
  for (int e=t; e<128*32; e+=256){
    int o = e>>5, ls = e&31;
    float v = tile[ls*129 + o];
    v = __fmaf_rn(v, s_a[o], s_b[o]);
    v = v > 0.f ? v : 0.f;
    ob[(size_t)o*NPOINT + s0 + ls] = v;
  }
}

extern "C" void kernel_launch(void* const* d_in, const int* in_sizes, int n_in,
                              void* d_out, int out_size, void* d_ws, size_t ws_size,
                              hipStream_t stream)
{
  const float* xyz    = (const float*)d_in[0];
  const float* points = (const float*)d_in[1];
  const float* W1 = (const float*)d_in[2];
  const float* b1 = (const float*)d_in[3];
  const float* g1 = (const float*)d_in[4];
  const float* be1= (const float*)d_in[5];
  const float* W2 = (const float*)d_in[6];
  const float* b2 = (const float*)d_in[7];
  const float* g2 = (const float*)d_in[8];
  const float* be2= (const float*)d_in[9];
  const float* W3 = (const float*)d_in[10];
  const float* b3 = (const float*)d_in[11];
  const float* g3 = (const float*)d_in[12];
  const float* be3= (const float*)d_in[13];
  float* out = (float*)d_out;
  char* ws = (char*)d_ws;
  float* z     = (float*)(ws);                            // 134,217,728
  float* pt    = (float*)(ws + 134217728);                //  16,777,216 (alias)
  float* gmax  = (float*)(ws + 134217728);                //   8,388,608
  float* part3 = (float*)(ws + 142606336);                //   4,194,304
  float* part2 = (float*)(ws + 146800640);                //   2,097,152
  float* part1 = (float*)(ws + 150994944);                //   2,097,152
  float* ab1   = (float*)(ws + 153092096);                //   512
  float* ab2   = (float*)(ws + 153092608);                //   512
  float* ab3   = (float*)(ws + 153093120);                //   1024

  hipLaunchKernelGGL(fps_kernel,      dim3(NB),   dim3(512), 0, stream, xyz, out);
  hipLaunchKernelGGL(transpose_kernel,dim3(1024), dim3(256), 0, stream, points, pt);
  hipLaunchKernelGGL(ballmlp1_kernel, dim3(4096), dim3(128), 0, stream, xyz, pt, out, W1, b1, z, part1);
  hipLaunchKernelGGL(reduce_kernel,   dim3(64),   dim3(64),  0, stream, part1, g1, be1, ab1, 64, 4096);
  hipLaunchKernelGGL(mlp2_kernel,     dim3(4096), dim3(128), 0, stream, z, ab1, W2, b2, part2);
  hipLaunchKernelGGL(reduce_kernel,   dim3(64),   dim3(64),  0, stream, part2, g2, be2, ab2, 64, 4096);
  hipLaunchKernelGGL(mlp3_kernel,     dim3(4096), dim3(256), 0, stream, z, ab2, W3, b3, gmax, part3);
  hipLaunchKernelGGL(reduce_kernel,   dim3(128),  dim3(64),  0, stream, part3, g3, be3, ab3, 128, 4096);
  hipLaunchKernelGGL(final_kernel,    dim3(512),  dim3(256), 0, stream, gmax, ab3, out);
}

// Round 14
// 2342.332 us; speedup vs baseline: 1.1262x; 1.0500x over previous
//
#include <hip/hip_runtime.h>
#include <hip/hip_bf16.h>
#include <stdint.h>

#define NB 8
#define NPTS 8192
#define NCH 64
#define NPOINT 2048
#define NSAMPLE 32
#define R2 0.04f

#define DPP_MAX_STEP(C) { \
  int lo2_ = __builtin_amdgcn_update_dpp(0, (int)(unsigned int)key, (C), 0xf, 0xf, true); \
  int hi2_ = __builtin_amdgcn_update_dpp(0, (int)(unsigned int)(key>>32), (C), 0xf, 0xf, true); \
  unsigned long long k2_ = ((unsigned long long)(unsigned int)hi2_ << 32) | (unsigned int)lo2_; \
  if (k2_ > key) key = k2_; }

// ---------------------------------------------------------------------------
// FPS (best known: R9): one block (512 thr = 8 waves) per batch.
// Exact IEEE replication; LDS point mirror; u64-key DPP wave-max; 1 barrier.
// ---------------------------------------------------------------------------
__global__ __launch_bounds__(512) void fps_kernel(const float* __restrict__ xyz,
                                                  float* __restrict__ out)
{
  const int t = threadIdx.x;
  const int wv = t >> 6, lane = t & 63;
  const int b = blockIdx.x;
  const float* xb = xyz + (size_t)b*3*NPTS;
  __shared__ float s_px[NPTS], s_py[NPTS], s_pz[NPTS];   // 96 KB point mirror
  __shared__ float s_ox[NPOINT], s_oy[NPOINT], s_oz[NPOINT]; // 24 KB out stash
  __shared__ unsigned long long s_key[2][8];
  for (int e=t; e<NPTS; e+=512){
    s_px[e]=xb[e]; s_py[e]=xb[NPTS+e]; s_pz[e]=xb[2*NPTS+e];
  }
  float px[16], py[16], pz[16], dist[16];
  const int base = (wv<<10) + lane;
  #pragma unroll
  for (int k=0;k<16;k++){
    int i = base + (k<<6);
    px[k]=xb[i]; py[k]=xb[NPTS+i]; pz[k]=xb[2*NPTS+i];
    dist[k]=1e10f;
  }
  __syncthreads();
  float cx = s_px[0], cy = s_py[0], cz = s_pz[0];   // far_0 = 0
  for (int s=0;s<NPOINT;s++){
    if (t==0){ s_ox[s]=cx; s_oy[s]=cy; s_oz[s]=cz; }
    float best = -1.0f; int bidx = 0;
    #pragma unroll
    for (int k=0;k<16;k++){
      float dx=__fsub_rn(px[k],cx), dy=__fsub_rn(py[k],cy), dz=__fsub_rn(pz[k],cz);
      float d = __fadd_rn(__fadd_rn(__fmul_rn(dx,dx),__fmul_rn(dy,dy)),__fmul_rn(dz,dz));
      float nd = d < dist[k] ? d : dist[k];
      dist[k]=nd;
      if (nd > best){ best = nd; bidx = base + (k<<6); }   // strict > keeps first idx
    }
    unsigned long long key = ((unsigned long long)__float_as_uint(best) << 13)
                           | (unsigned long long)(8191 - bidx);
    DPP_MAX_STEP(0x111)
    DPP_MAX_STEP(0x112)
    DPP_MAX_STEP(0x114)
    DPP_MAX_STEP(0x118)
    DPP_MAX_STEP(0x142)
    DPP_MAX_STEP(0x143)
    if (lane==63) s_key[s&1][wv] = key;
    __syncthreads();
    const unsigned long long* kr = s_key[s&1];
    unsigned long long k0=kr[0],k1=kr[1],k2=kr[2],k3=kr[3],
                       k4=kr[4],k5=kr[5],k6=kr[6],k7=kr[7];
    unsigned long long m01=k0>k1?k0:k1, m23=k2>k3?k2:k3;
    unsigned long long m45=k4>k5?k4:k5, m67=k6>k7?k6:k7;
    unsigned long long m03=m01>m23?m01:m23, m47=m45>m67?m45:m67;
    unsigned long long mk = m03>m47?m03:m47;
    const int far = 8191 - (int)(mk & 8191ull);
    cx = s_px[far]; cy = s_py[far]; cz = s_pz[far];
  }
  __syncthreads();
  float* oxb = out + (size_t)b*3*NPOINT;
  for (int e=t; e<NPOINT; e+=512){
    oxb[e]          = s_ox[e];
    oxb[NPOINT+e]   = s_oy[e];
    oxb[2*NPOINT+e] = s_oz[e];
  }
}

// ---------------------------------------------------------------------------
// Transpose points [b][c][n] -> pt [b][n][c]
// ---------------------------------------------------------------------------
__global__ __launch_bounds__(256) void transpose_kernel(const float* __restrict__ points,
                                                        float* __restrict__ pt)
{
  __shared__ float tile[64][65];
  const int t = threadIdx.x;
  const int b  = blockIdx.x >> 7;
  const int n0 = (blockIdx.x & 127) << 6;
  const int tx = t & 63, ty = t >> 6;
  #pragma unroll
  for (int r=0; r<16; r++){
    const int c = ty*16 + r;
    tile[c][tx] = points[(size_t)b*NCH*NPTS + (size_t)c*NPTS + n0 + tx];
  }
  __syncthreads();
  #pragma unroll
  for (int r=0; r<16; r++){
    const int n = ty*16 + r;
    pt[((size_t)b*NPTS + n0 + n)*64 + tx] = tile[tx][n];
  }
}

// ---------------------------------------------------------------------------
// Fused ball query + MLP layer 1, register-tiled GEMM (8 samples x 8 outs).
// ---------------------------------------------------------------------------
__global__ __launch_bounds__(128) void ballmlp1_kernel(
    const float* __restrict__ xyz, const float* __restrict__ pt,
    const float* __restrict__ nxyz,
    const float* __restrict__ W1, const float* __restrict__ b1,
    float* __restrict__ z, float* __restrict__ part)
{
  __shared__ float wl[67*64];        // W [c][o]
  __shared__ float fl[67*128];       // f [c][s]; reused for stats staging
  __shared__ int s_buf[4][NSAMPLE];
  __shared__ int s_cnt[4];
  __shared__ float s_ctr[4][3];
  const int t = threadIdx.x;
  const int blk = blockIdx.x;
  for (int e=t; e<67*64; e+=128){
    int o = e/67, c = e - o*67;
    wl[c*64+o] = W1[e];
  }
  const int wv = t>>6, lane = t&63;
  for (int sub=0; sub<2; sub++){
    const int gi2 = wv*2 + sub;
    const int g = blk*4 + gi2;
    const int b = g >> 11;
    const int s = g & 2047;
    const float* ob = nxyz + (size_t)b*3*NPOINT;
    const float cx = ob[s], cy = ob[NPOINT+s], cz = ob[2*NPOINT+s];
    if (lane==0){ s_ctr[gi2][0]=cx; s_ctr[gi2][1]=cy; s_ctr[gi2][2]=cz; }
    const float csum = __fadd_rn(__fadd_rn(__fmul_rn(cx,cx),__fmul_rn(cy,cy)),__fmul_rn(cz,cz));
    const float* xb = xyz + (size_t)b*3*NPTS;
    int cnt = 0;
    for (int c0=0; c0<NPTS; c0+=64){
      const int i = c0 + lane;
      float x=xb[i], y=xb[NPTS+i], zz=xb[2*NPTS+i];
      float dot  = __fmaf_rn(cz, zz, __fmaf_rn(cy, y, __fmul_rn(cx, x)));
      float dsum = __fadd_rn(__fadd_rn(__fmul_rn(x,x),__fmul_rn(y,y)),__fmul_rn(zz,zz));
      float sqr  = __fadd_rn(__fadd_rn(__fmul_rn(-2.0f,dot), csum), dsum);
      bool in = (sqr <= R2);
      unsigned long long mm = __ballot(in);
      int rank = cnt + __popcll(mm & ((1ull<<lane)-1ull));
      if (in && rank < NSAMPLE) s_buf[gi2][rank] = i;
      cnt += (int)__popcll(mm);
      if (cnt >= NSAMPLE) break;
    }
    if (lane==0) s_cnt[gi2] = cnt;
  }
  __syncthreads();
  {
    const int gi = t>>5, lane2 = t&31;
    const int g = blk*4 + gi;
    const int b = g >> 11;
    const int cnt = s_cnt[gi];
    const int first = s_buf[gi][0];
    const int idx = (lane2 < cnt) ? s_buf[gi][lane2] : first;
    const float* xb = xyz + (size_t)b*3*NPTS;
    fl[0*128+t] = __fsub_rn(xb[idx],        s_ctr[gi][0]);
    fl[1*128+t] = __fsub_rn(xb[NPTS+idx],   s_ctr[gi][1]);
    fl[2*128+t] = __fsub_rn(xb[2*NPTS+idx], s_ctr[gi][2]);
    const float* pr = pt + ((size_t)b*NPTS + idx)*64;
    #pragma unroll
    for (int q=0;q<16;q++){
      float4 v = *(const float4*)(pr + q*4);
      fl[(3+q*4+0)*128+t]=v.x; fl[(3+q*4+1)*128+t]=v.y;
      fl[(3+q*4+2)*128+t]=v.z; fl[(3+q*4+3)*128+t]=v.w;
    }
  }
  __syncthreads();
  const int tx = t & 15, ty = t >> 4;
  float acc[64];
  #pragma unroll
  for (int i=0;i<64;i++) acc[i]=0.0f;
  for (int c=0;c<67;c++){
    float4 fa = *(const float4*)&fl[c*128 + tx*8];
    float4 fb = *(const float4*)&fl[c*128 + tx*8 + 4];
    float4 wa = *(const float4*)&wl[c*64 + ty*8];
    float4 wb = *(const float4*)&wl[c*64 + ty*8 + 4];
    float fv[8] = {fa.x,fa.y,fa.z,fa.w,fb.x,fb.y,fb.z,fb.w};
    float wv8[8] = {wa.x,wa.y,wa.z,wa.w,wb.x,wb.y,wb.z,wb.w};
    #pragma unroll
    for (int oo=0;oo<8;oo++)
      #pragma unroll
      for (int ss=0;ss<8;ss++)
        acc[oo*8+ss] = __fmaf_rn(fv[ss], wv8[oo], acc[oo*8+ss]);
  }
  #pragma unroll
  for (int oo=0;oo<8;oo++){
    const float bb = b1[ty*8+oo];
    #pragma unroll
    for (int ss=0;ss<8;ss++) acc[oo*8+ss] = __fadd_rn(acc[oo*8+ss], bb);
  }
  float* zb = z + (size_t)blk*8192;
  #pragma unroll
  for (int oo=0;oo<8;oo++){
    float4 v0; v0.x=acc[oo*8+0]; v0.y=acc[oo*8+1]; v0.z=acc[oo*8+2]; v0.w=acc[oo*8+3];
    float4 v1; v1.x=acc[oo*8+4]; v1.y=acc[oo*8+5]; v1.z=acc[oo*8+6]; v1.w=acc[oo*8+7];
    *(float4*)(zb + (ty*8+oo)*128 + tx*8)     = v0;
    *(float4*)(zb + (ty*8+oo)*128 + tx*8 + 4) = v1;
  }
  __syncthreads();
  float* spA = fl;                 // [64][17]
  float* spQ = fl + 64*17;
  #pragma unroll
  for (int oo=0;oo<8;oo++){
    float sA=0.f, sQ=0.f;
    #pragma unroll
    for (int ss=0;ss<8;ss++){
      float v = acc[oo*8+ss];
      sA += v; sQ = __fmaf_rn(v,v,sQ);
    }
    spA[(ty*8+oo)*17 + tx] = sA;
    spQ[(ty*8+oo)*17 + tx] = sQ;
  }
  __syncthreads();
  if (t < 64){
    float A=0.f, Q=0.f;
    #pragma unroll
    for (int j=0;j<16;j++){ A += spA[t*17+j]; Q += spQ[t*17+j]; }
    part[(size_t)blk*128 + t]      = A;
    part[(size_t)blk*128 + 64 + t] = Q;
  }
}

// ---------------------------------------------------------------------------
// MLP layer 2: register-tiled GEMM, in-place z tile update.
// ---------------------------------------------------------------------------
__global__ __launch_bounds__(128) void mlp2_kernel(
    float* __restrict__ z, const float* __restrict__ ab1,
    const float* __restrict__ W2, const float* __restrict__ b2,
    float* __restrict__ part)
{
  __shared__ float wl[64*64];
  __shared__ float fl[64*128];
  __shared__ float s_ab[128];
  const int t = threadIdx.x;
  for (int e=t; e<64*64; e+=128){
    int o = e>>6, c = e&63;
    wl[c*64+o] = W2[e];
  }
  if (t<128) s_ab[t] = ab1[t];
  __syncthreads();
  float* zb = z + (size_t)blockIdx.x*8192;
  for (int c=0;c<64;c++){
    float v = zb[c*128 + t];
    float a = __fmaf_rn(v, s_ab[c], s_ab[64+c]);
    fl[c*128 + t] = a > 0.f ? a : 0.f;
  }
  __syncthreads();
  const int tx = t & 15, ty = t >> 4;
  float acc[64];
  #pragma unroll
  for (int i=0;i<64;i++) acc[i]=0.0f;
  for (int c=0;c<64;c++){
    float4 fa = *(const float4*)&fl[c*128 + tx*8];
    float4 fb = *(const float4*)&fl[c*128 + tx*8 + 4];
    float4 wa = *(const float4*)&wl[c*64 + ty*8];
    float4 wb = *(const float4*)&wl[c*64 + ty*8 + 4];
    float fv[8] = {fa.x,fa.y,fa.z,fa.w,fb.x,fb.y,fb.z,fb.w};
    float wv8[8] = {wa.x,wa.y,wa.z,wa.w,wb.x,wb.y,wb.z,wb.w};
    #pragma unroll
    for (int oo=0;oo<8;oo++)
      #pragma unroll
      for (int ss=0;ss<8;ss++)
        acc[oo*8+ss] = __fmaf_rn(fv[ss], wv8[oo], acc[oo*8+ss]);
  }
  #pragma unroll
  for (int oo=0;oo<8;oo++){
    const float bb = b2[ty*8+oo];
    #pragma unroll
    for (int ss=0;ss<8;ss++) acc[oo*8+ss] = __fadd_rn(acc[oo*8+ss], bb);
  }
  #pragma unroll
  for (int oo=0;oo<8;oo++){
    float4 v0; v0.x=acc[oo*8+0]; v0.y=acc[oo*8+1]; v0.z=acc[oo*8+2]; v0.w=acc[oo*8+3];
    float4 v1; v1.x=acc[oo*8+4]; v1.y=acc[oo*8+5]; v1.z=acc[oo*8+6]; v1.w=acc[oo*8+7];
    *(float4*)(zb + (ty*8+oo)*128 + tx*8)     = v0;
    *(float4*)(zb + (ty*8+oo)*128 + tx*8 + 4) = v1;
  }
  __syncthreads();
  float* spA = fl;
  float* spQ = fl + 64*17;
  #pragma unroll
  for (int oo=0;oo<8;oo++){
    float sA=0.f, sQ=0.f;
    #pragma unroll
    for (int ss=0;ss<8;ss++){
      float v = acc[oo*8+ss];
      sA += v; sQ = __fmaf_rn(v,v,sQ);
    }
    spA[(ty*8+oo)*17 + tx] = sA;
    spQ[(ty*8+oo)*17 + tx] = sQ;
  }
  __syncthreads();
  if (t < 64){
    float A=0.f, Q=0.f;
    #pragma unroll
    for (int j=0;j<16;j++){ A += spA[t*17+j]; Q += spQ[t*17+j]; }
    part[(size_t)blockIdx.x*128 + t]      = A;
    part[(size_t)blockIdx.x*128 + 64 + t] = Q;
  }
}

// ---------------------------------------------------------------------------
// MLP layer 3 + group max: 256 thr, tile 128 samples x 128 outs (8x8/thread).
// ---------------------------------------------------------------------------
__global__ __launch_bounds__(256) void mlp3_kernel(
    const float* __restrict__ z, const float* __restrict__ ab2,
    const float* __restrict__ W3, const float* __restrict__ b3,
    float* __restrict__ gmax, float* __restrict__ part)
{
  __shared__ float wl[64*128];       // W [c][o]; reused: spA/spQ [128][17]
  __shared__ float fl[64*128];       // f [c][s]; reused: sm [16][132]
  __shared__ float s_ab[128];
  const int t = threadIdx.x;
  const int blk = blockIdx.x;
  for (int e=t; e<64*128; e+=256){
    int o = e>>6, c = e&63;
    wl[c*128+o] = W3[e];
  }
  if (t<128) s_ab[t] = ab2[t];
  __syncthreads();
  const float* zb = z + (size_t)blk*8192;
  for (int e=t; e<64*128; e+=256){
    int c = e>>7, s = e&127;
    float v = zb[c*128 + s];
    float a = __fmaf_rn(v, s_ab[c], s_ab[64+c]);
    fl[c*128 + s] = a > 0.f ? a : 0.f;
  }
  __syncthreads();
  const int tx = t & 15, ty = t >> 4;
  float acc[64];
  #pragma unroll
  for (int i=0;i<64;i++) acc[i]=0.0f;
  for (int c=0;c<64;c++){
    float4 fa = *(const float4*)&fl[c*128 + tx*8];
    float4 fb = *(const float4*)&fl[c*128 + tx*8 + 4];
    float4 wa = *(const float4*)&wl[c*128 + ty*8];
    float4 wb = *(const float4*)&wl[c*128 + ty*8 + 4];
    float fv[8] = {fa.x,fa.y,fa.z,fa.w,fb.x,fb.y,fb.z,fb.w};
    float wv8[8] = {wa.x,wa.y,wa.z,wa.w,wb.x,wb.y,wb.z,wb.w};
    #pragma unroll
    for (int oo=0;oo<8;oo++)
      #pragma unroll
      for (int ss=0;ss<8;ss++)
        acc[oo*8+ss] = __fmaf_rn(fv[ss], wv8[oo], acc[oo*8+ss]);
  }
  #pragma unroll
  for (int oo=0;oo<8;oo++){
    const float bb = b3[ty*8+oo];
    #pragma unroll
    for (int ss=0;ss<8;ss++) acc[oo*8+ss] = __fadd_rn(acc[oo*8+ss], bb);
  }
  __syncthreads();
  float* spA = wl;                    // [128][17]
  float* spQ = wl + 128*17;
  float* sm  = fl;                    // [16][132]
  #pragma unroll
  for (int oo=0;oo<8;oo++){
    float sA=0.f, sQ=0.f, mx=acc[oo*8+0];
    #pragma unroll
    for (int ss=0;ss<8;ss++){
      float v = acc[oo*8+ss];
      sA += v; sQ = __fmaf_rn(v,v,sQ);
      mx = v > mx ? v : mx;
    }
    spA[(ty*8+oo)*17 + tx] = sA;
    spQ[(ty*8+oo)*17 + tx] = sQ;
    sm[tx*132 + ty*8+oo] = mx;
  }
  __syncthreads();
  if (t < 128){
    float A=0.f, Q=0.f;
    #pragma unroll
    for (int j=0;j<16;j++){ A += spA[t*17+j]; Q += spQ[t*17+j]; }
    part[(size_t)blk*256 + t]       = A;
    part[(size_t)blk*256 + 128 + t] = Q;
  }
  #pragma unroll
  for (int r=0;r<2;r++){
    const int id = t + r*256;
    const int g = id >> 7, o = id & 127;
    float m0 = sm[(g*4+0)*132 + o];
    float m1 = sm[(g*4+1)*132 + o];
    float m2 = sm[(g*4+2)*132 + o];
    float m3 = sm[(g*4+3)*132 + o];
    float mm = m0 > m1 ? m0 : m1;
    float nn = m2 > m3 ? m2 : m3;
    mm = mm > nn ? mm : nn;
    gmax[((size_t)blk*4 + g)*128 + o] = mm;
  }
}

// ---------------------------------------------------------------------------
// BN stats finalize
// ---------------------------------------------------------------------------
__global__ __launch_bounds__(64) void reduce_kernel(const float* __restrict__ part,
    const float* __restrict__ gw, const float* __restrict__ bew,
    float* __restrict__ ab, int cout, int nblk)
{
  const int o = blockIdx.x, t = threadIdx.x;
  const int stride = 2*cout;
  float A=0.f, Q=0.f;
  for (int i=t;i<nblk;i+=64){
    A += part[(size_t)i*stride + o];
    Q += part[(size_t)i*stride + cout + o];
  }
  #pragma unroll
  for (int off=1; off<64; off<<=1){
    A += __shfl_xor(A, off, 64);
    Q += __shfl_xor(Q, off, 64);
  }
  if (t==0){
    const float inv = 1.0f/524288.0f;
    float mean = A*inv;
    float var  = Q*inv - mean*mean;
    float a = gw[o] / sqrtf(var + 1e-5f);
    ab[o] = a;
    ab[cout+o] = bew[o] - mean*a;
  }
}

// ---------------------------------------------------------------------------
// Final: out_points[b][o][s] = relu(gmax*a3 + shift3), transposed tile
// ---------------------------------------------------------------------------
__global__ __launch_bounds__(256) void final_kernel(const float* __restrict__ gmax,
    const float* __restrict__ ab3, float* __restrict__ out)
{
  __shared__ float tile[32*129];
  __shared__ float s_a[128], s_b[128];
  const int t = threadIdx.x;
  const int b = blockIdx.x >> 6;
  const int s0 = (blockIdx.x & 63)*32;
  if (t<128){ s_a[t]=ab3[t]; s_b[t]=ab3[128+t]; }
  const float* gp = gmax + ((size_t)b*NPOINT + s0)*128;
  for (int e=t; e<32*32; e+=256){
    int r = e>>5, q = e&31;
    float4 v = *(const float4*)(gp + r*128 + q*4);
    tile[r*129 + q*4+0]=v.x; tile[r*129 + q*4+1]=v.y;
    tile[r*129 + q*4+2]=v.z; tile[r*129 + q*4+3]=v.w;
  }
  __syncthreads();
  float* ob = out + 49152 + (size_t)b*128*NPOINT;
  for (int e=t; e<128*32; e+=256){
    int o = e>>5, ls = e&31;
    float v = tile[ls*129 + o];
    v = __fmaf_rn(v, s_a[o], s_b[o]);
    v = v > 0.f ? v : 0.f;
    ob[(size_t)o*NPOINT + s0 + ls] = v;
  }
}

extern "C" void kernel_launch(void* const* d_in, const int* in_sizes, int n_in,
                              void* d_out, int out_size, void* d_ws, size_t ws_size,
                              hipStream_t stream)
{
  const float* xyz    = (const float*)d_in[0];
  const float* points = (const float*)d_in[1];
  const float* W1 = (const float*)d_in[2];
  const float* b1 = (const float*)d_in[3];
  const float* g1 = (const float*)d_in[4];
  const float* be1= (const float*)d_in[5];
  const float* W2 = (const float*)d_in[6];
  const float* b2 = (const float*)d_in[7];
  const float* g2 = (const float*)d_in[8];
  const float* be2= (const float*)d_in[9];
  const float* W3 = (const float*)d_in[10];
  const float* b3 = (const float*)d_in[11];
  const float* g3 = (const float*)d_in[12];
  const float* be3= (const float*)d_in[13];
  float* out = (float*)d_out;
  char* ws = (char*)d_ws;
  float* z     = (float*)(ws);                            // 134,217,728
  float* pt    = (float*)(ws + 134217728);                //  16,777,216 (alias)
  float* gmax  = (float*)(ws + 134217728);                //   8,388,608
  float* part3 = (float*)(ws + 142606336);                //   4,194,304
  float* part2 = (float*)(ws + 146800640);                //   2,097,152
  float* part1 = (float*)(ws + 150994944);                //   2,097,152
  float* ab1   = (float*)(ws + 153092096);                //   512
  float* ab2   = (float*)(ws + 153092608);                //   512
  float* ab3   = (float*)(ws + 153093120);                //   1024

  hipLaunchKernelGGL(fps_kernel,      dim3(NB),   dim3(512), 0, stream, xyz, out);
  hipLaunchKernelGGL(transpose_kernel,dim3(1024), dim3(256), 0, stream, points, pt);
  hipLaunchKernelGGL(ballmlp1_kernel, dim3(4096), dim3(128), 0, stream, xyz, pt, out, W1, b1, z, part1);
  hipLaunchKernelGGL(reduce_kernel,   dim3(64),   dim3(64),  0, stream, part1, g1, be1, ab1, 64, 4096);
  hipLaunchKernelGGL(mlp2_kernel,     dim3(4096), dim3(128), 0, stream, z, ab1, W2, b2, part2);
  hipLaunchKernelGGL(reduce_kernel,   dim3(64),   dim3(64),  0, stream, part2, g2, be2, ab2, 64, 4096);
  hipLaunchKernelGGL(mlp3_kernel,     dim3(4096), dim3(256), 0, stream, z, ab2, W3, b3, gmax, part3);
  hipLaunchKernelGGL(reduce_kernel,   dim3(128),  dim3(64),  0, stream, part3, g3, be3, ab3, 128, 4096);
  hipLaunchKernelGGL(final_kernel,    dim3(512),  dim3(256), 0, stream, gmax, ab3, out);
}